// Round 8
// baseline (377.692 us; speedup 1.0000x reference)
//
#include <hip/hip_runtime.h>

#define NMS_NUM_CLASSES 16
#define NMS_N 2048
#define NMS_IOU_TH 0.5f
#define NMS_SCORE_TH 0.05f
#define NMS_MAX_DET 100
#define NMS_MAX_PER_CLASS 100
#define NMS_NS (NMS_NUM_CLASSES * NMS_MAX_PER_CLASS)   // 1600

// ---------------------------------------------------------------------------
// Kernel 1: one block per (image, class). Round-4 proven structure; only the
// greedy loop (barrier per kept candidate instead of per candidate) and the
// emit prefix scan (wave scan instead of serial) are changed.
// ---------------------------------------------------------------------------
__global__ __launch_bounds__(256) void nms_per_class_kernel(
    const float* __restrict__ pred,   // [B, N, 6] x1,y1,x2,y2,cls,score
    float* __restrict__ ws_scores,    // [B, 1600]
    float* __restrict__ ws_boxes,     // [B, 1600, 4]
    float* __restrict__ out,          // [B*600] rows + [B] nvalid
    int B)
{
    const int b = blockIdx.x / NMS_NUM_CLASSES;
    const int c = blockIdx.x % NMS_NUM_CLASSES;
    const float* p = pred + (size_t)b * NMS_N * 6;

    // zero-init output for this image (k2 is a later dispatch on the stream)
    if (c == 0) {
        float* ob = out + (size_t)b * NMS_MAX_DET * 6;
        for (int t = threadIdx.x; t < NMS_MAX_DET * 6; t += blockDim.x) ob[t] = 0.0f;
        if (threadIdx.x == 0) out[(size_t)B * NMS_MAX_DET * 6 + b] = 0.0f;
    }

    // unsorted candidate arrays
    __shared__ float s_scu[NMS_N];
    __shared__ int   s_ixu[NMS_N];
    __shared__ float s_bxu[NMS_N * 4];
    // sorted candidate arrays
    __shared__ float s_sc[NMS_N];
    __shared__ float s_bx[NMS_N * 4];
    __shared__ unsigned char s_keep[NMS_N];
    __shared__ int s_m;
    __shared__ int s_part[256];
    __shared__ int s_total;
    __shared__ int s_next;

    if (threadIdx.x == 0) s_m = 0;
    __syncthreads();

    // --- compact candidates of class c with score > TH ---
    const float2* p2 = (const float2*)p;   // row i = p2[3i], p2[3i+1], p2[3i+2]
    for (int i = threadIdx.x; i < NMS_N; i += blockDim.x) {
        float2 v0 = p2[i * 3 + 0];   // x1, y1
        float2 v1 = p2[i * 3 + 1];   // x2, y2
        float2 v2 = p2[i * 3 + 2];   // cls, score
        if ((int)v2.x == c && v2.y > NMS_SCORE_TH) {
            int pos = atomicAdd(&s_m, 1);
            s_scu[pos] = v2.y;
            s_ixu[pos] = i;
            s_bxu[pos * 4 + 0] = v0.x;
            s_bxu[pos * 4 + 1] = v0.y;
            s_bxu[pos * 4 + 2] = v1.x;
            s_bxu[pos * 4 + 3] = v1.y;
        }
    }
    __syncthreads();
    const int M = s_m;

    // --- rank sort: desc score, ties -> lower original index first ---
    for (int q = threadIdx.x; q < M; q += blockDim.x) {
        float sq = s_scu[q];
        int   iq = s_ixu[q];
        int rk = 0;
        for (int j = 0; j < M; ++j) {
            float sj = s_scu[j];
            rk += (sj > sq) || (sj == sq && s_ixu[j] < iq);
        }
        s_sc[rk] = sq;
        s_bx[rk * 4 + 0] = s_bxu[q * 4 + 0];
        s_bx[rk * 4 + 1] = s_bxu[q * 4 + 1];
        s_bx[rk * 4 + 2] = s_bxu[q * 4 + 2];
        s_bx[rk * 4 + 3] = s_bxu[q * 4 + 3];
        s_keep[rk] = 1;
    }
    __syncthreads();

    // --- greedy NMS over kept candidates only ---
    // Invariant: all suppressions by kept candidates < i are applied before
    // the next-kept search (barrier after suppression), so iterating only
    // surviving candidates is exactly the reference greedy order.
    int i = 0;
    while (i < M) {
        if (threadIdx.x == 0) s_next = M;
        __syncthreads();
        {
            int cand = i + threadIdx.x;
            if (cand < M && s_keep[cand]) atomicMin(&s_next, cand);
        }
        __syncthreads();
        const int ni = s_next;
        if (ni >= M) { i += blockDim.x; continue; }   // no kept in window

        float x1 = s_bx[ni * 4 + 0], y1 = s_bx[ni * 4 + 1];
        float x2 = s_bx[ni * 4 + 2], y2 = s_bx[ni * 4 + 3];
        float ai = (y2 - y1) * (x2 - x1);
        for (int j = ni + 1 + threadIdx.x; j < M; j += blockDim.x) {
            if (!s_keep[j]) continue;
            float bx1 = s_bx[j * 4 + 0], by1 = s_bx[j * 4 + 1];
            float bx2 = s_bx[j * 4 + 2], by2 = s_bx[j * 4 + 3];
            float aj = (by2 - by1) * (bx2 - bx1);
            float ih = fminf(y2, by2) - fmaxf(y1, by1);
            ih = fmaxf(ih, 0.0f);
            float iw = fminf(x2, bx2) - fmaxf(x1, bx1);
            iw = fmaxf(iw, 0.0f);
            float inter = ih * iw;
            float uni = ai + aj - inter;
            float iou = (inter > 0.0f) ? inter / fmaxf(uni, 1e-08f) : 0.0f;
            if (iou > NMS_IOU_TH) s_keep[j] = 0;
        }
        __syncthreads();
        i = ni + 1;
    }
    __syncthreads();

    // --- emit top-100 kept in sorted order via block scan; pad with -1 ---
    const int chunk = (M + 255) / 256;           // contiguous slots per thread
    const int lo = threadIdx.x * chunk;
    const int hi = (lo + chunk < M) ? (lo + chunk) : M;
    int cnt = 0;
    for (int j = lo; j < hi; ++j) cnt += s_keep[j];
    s_part[threadIdx.x] = cnt;
    __syncthreads();
    // wave-0 shfl scan over the 256 partials (4 per lane)
    if (threadIdx.x < 64) {
        const int base = threadIdx.x * 4;
        int v0 = s_part[base + 0], v1 = s_part[base + 1];
        int v2 = s_part[base + 2], v3 = s_part[base + 3];
        int sum = v0 + v1 + v2 + v3;
        int inc = sum;
        for (int off = 1; off < 64; off <<= 1) {
            int n = __shfl_up(inc, off, 64);
            if ((int)threadIdx.x >= off) inc += n;
        }
        int exc = inc - sum;
        s_part[base + 0] = exc;
        s_part[base + 1] = exc + v0;
        s_part[base + 2] = exc + v0 + v1;
        s_part[base + 3] = exc + v0 + v1 + v2;
        if (threadIdx.x == 63) s_total = inc;
    }
    __syncthreads();

    float* osc = ws_scores + ((size_t)b * NMS_NUM_CLASSES + c) * NMS_MAX_PER_CLASS;
    float* obx = ws_boxes + (((size_t)b * NMS_NUM_CLASSES + c) * NMS_MAX_PER_CLASS) * 4;
    int pos = s_part[threadIdx.x];
    for (int j = lo; j < hi; ++j) {
        if (s_keep[j]) {
            if (pos < NMS_MAX_PER_CLASS) {
                osc[pos] = s_sc[j];
                obx[pos * 4 + 0] = s_bx[j * 4 + 0];
                obx[pos * 4 + 1] = s_bx[j * 4 + 1];
                obx[pos * 4 + 2] = s_bx[j * 4 + 2];
                obx[pos * 4 + 3] = s_bx[j * 4 + 3];
            }
            pos++;
        }
    }
    // pad positions [total, 100) with -1
    if (threadIdx.x < NMS_MAX_PER_CLASS && threadIdx.x >= s_total)
        osc[threadIdx.x] = -1.0f;
}

// ---------------------------------------------------------------------------
// Kernel 2: one block per (image, class). Cross-class top-100 of the 1600
// slot scores (ties -> lower flat slot index, matching JAX top_k); scatter
// rows; nvalid via ballot (count of rk<100 & valid == min(#valid,100)).
// (unchanged from round 4)
// ---------------------------------------------------------------------------
__global__ __launch_bounds__(128) void nms_topk_kernel(
    const float* __restrict__ ws_scores,   // [B, 1600]
    const float* __restrict__ ws_boxes,    // [B, 1600, 4]
    float* __restrict__ out,               // [B*600] rows + [B] nvalid
    int B)
{
    const int b = blockIdx.x / NMS_NUM_CLASSES;
    const int c = blockIdx.x % NMS_NUM_CLASSES;
    __shared__ float s_sc[NMS_NS];

    const float* isc = ws_scores + (size_t)b * NMS_NS;
    for (int t = threadIdx.x; t < NMS_NS; t += blockDim.x) s_sc[t] = isc[t];
    __syncthreads();

    int is_top = 0;
    const int t = threadIdx.x;
    if (t < NMS_MAX_PER_CLASS) {
        const int slot = c * NMS_MAX_PER_CLASS + t;
        float s = s_sc[slot];
        if (s > NMS_SCORE_TH) {
            int rk = 0;
            for (int j = 0; j < NMS_NS; ++j) {
                float sj = s_sc[j];
                rk += (sj > s) || (sj == s && j < slot);
            }
            if (rk < NMS_MAX_DET) {
                const float* bx = ws_boxes + ((size_t)b * NMS_NS + slot) * 4;
                float* row = out + (size_t)b * NMS_MAX_DET * 6 + rk * 6;
                row[0] = bx[0];
                row[1] = bx[1];
                row[2] = bx[2];
                row[3] = bx[3];
                row[4] = (float)c;
                row[5] = s;
                is_top = 1;
            }
        }
    }
    unsigned long long m = __ballot(is_top);
    if ((threadIdx.x & 63) == 0) {
        float cnt = (float)__popcll(m);
        if (cnt > 0.0f)
            atomicAdd(&out[(size_t)B * NMS_MAX_DET * 6 + b], cnt);
    }
}

extern "C" void kernel_launch(void* const* d_in, const int* in_sizes, int n_in,
                              void* d_out, int out_size, void* d_ws, size_t ws_size,
                              hipStream_t stream) {
    const float* pred = (const float*)d_in[0];
    const int B = in_sizes[0] / (NMS_N * 6);
    if (B <= 0) return;
    float* out = (float*)d_out;

    float* ws_scores = (float*)d_ws;
    float* ws_boxes = ws_scores + (size_t)B * NMS_NS;

    nms_per_class_kernel<<<dim3(B * NMS_NUM_CLASSES), dim3(256), 0, stream>>>(
        pred, ws_scores, ws_boxes, out, B);
    nms_topk_kernel<<<dim3(B * NMS_NUM_CLASSES), dim3(128), 0, stream>>>(
        ws_scores, ws_boxes, out, B);
}

// Round 11
// 174.824 us; speedup vs baseline: 2.1604x; 2.1604x over previous
//
#include <hip/hip_runtime.h>

#define NMS_NUM_CLASSES 16
#define NMS_N 2048
#define NMS_IOU_TH 0.5f
#define NMS_SCORE_TH 0.05f
#define NMS_MAX_DET 100
#define NMS_MAX_PER_CLASS 100
#define NMS_NS (NMS_NUM_CLASSES * NMS_MAX_PER_CLASS)   // 1600

// NOTE (session pitfall): casting __shared__ float arrays to float4* emits
// ds_read_b128 with an alignment promise the LDS allocator does not keep —
// 5/5 kernels with that cast died with container-level faults; all scalar-
// LDS kernels passed. Scalar LDS reads only in this file.

// ---------------------------------------------------------------------------
// Kernel 1: one block per (image, class). Compact -> rank sort (r4-proven) ->
// wave-0 serial greedy NMS with register keep-masks (no barriers/atomics in
// the loop) -> wave-scan emit (r8-proven). c==0 blocks zero image output.
// ---------------------------------------------------------------------------
__global__ __launch_bounds__(256) void nms_per_class_kernel(
    const float* __restrict__ pred,   // [B, N, 6] x1,y1,x2,y2,cls,score
    float* __restrict__ ws_scores,    // [B, 1600]
    float* __restrict__ ws_boxes,     // [B, 1600, 4]
    float* __restrict__ out,          // [B*600] rows + [B] nvalid
    int B)
{
    const int b = blockIdx.x / NMS_NUM_CLASSES;
    const int c = blockIdx.x % NMS_NUM_CLASSES;
    const float* p = pred + (size_t)b * NMS_N * 6;

    // zero-init output for this image (k2 is a later dispatch on the stream)
    if (c == 0) {
        float* ob = out + (size_t)b * NMS_MAX_DET * 6;
        for (int t = threadIdx.x; t < NMS_MAX_DET * 6; t += blockDim.x) ob[t] = 0.0f;
        if (threadIdx.x == 0) out[(size_t)B * NMS_MAX_DET * 6 + b] = 0.0f;
    }

    // unsorted candidate arrays
    __shared__ float s_scu[NMS_N];
    __shared__ int   s_ixu[NMS_N];
    __shared__ float s_bxu[NMS_N * 4];
    // sorted candidate arrays
    __shared__ float s_sc[NMS_N];
    __shared__ float s_bx[NMS_N * 4];
    __shared__ unsigned char s_keep[NMS_N];
    __shared__ int s_m;
    __shared__ int s_part[256];
    __shared__ int s_total;

    if (threadIdx.x == 0) s_m = 0;
    __syncthreads();

    // --- compact candidates of class c with score > TH ---
    const float2* p2 = (const float2*)p;   // row i = p2[3i], p2[3i+1], p2[3i+2]
    for (int i = threadIdx.x; i < NMS_N; i += blockDim.x) {
        float2 v0 = p2[i * 3 + 0];   // x1, y1
        float2 v1 = p2[i * 3 + 1];   // x2, y2
        float2 v2 = p2[i * 3 + 2];   // cls, score
        if ((int)v2.x == c && v2.y > NMS_SCORE_TH) {
            int pos = atomicAdd(&s_m, 1);
            s_scu[pos] = v2.y;
            s_ixu[pos] = i;
            s_bxu[pos * 4 + 0] = v0.x;
            s_bxu[pos * 4 + 1] = v0.y;
            s_bxu[pos * 4 + 2] = v1.x;
            s_bxu[pos * 4 + 3] = v1.y;
        }
    }
    __syncthreads();
    const int M = s_m;

    // --- rank sort: desc score, ties -> lower original index first ---
    for (int q = threadIdx.x; q < M; q += blockDim.x) {
        float sq = s_scu[q];
        int   iq = s_ixu[q];
        int rk = 0;
        for (int j = 0; j < M; ++j) {
            float sj = s_scu[j];
            rk += (sj > sq) || (sj == sq && s_ixu[j] < iq);
        }
        s_sc[rk] = sq;
        s_bx[rk * 4 + 0] = s_bxu[q * 4 + 0];
        s_bx[rk * 4 + 1] = s_bxu[q * 4 + 1];
        s_bx[rk * 4 + 2] = s_bxu[q * 4 + 2];
        s_bx[rk * 4 + 3] = s_bxu[q * 4 + 3];
    }
    __syncthreads();

    // --- wave-0 serial greedy NMS, register keep-masks ---
    // Candidate j owned by lane (j&63), bit (j>>6). Suppressions land in the
    // owner's register during iteration i' < i; the shfl at i reads the
    // current mask -> exact reference greedy order. No barriers, no atomics.
    if (threadIdx.x < 64) {
        const int lane = threadIdx.x;
        const int nslots = (M + 63) >> 6;
        unsigned int keep = 0;
        for (int s = 0; s < nslots; ++s)
            if ((s << 6) + lane < M) keep |= (1u << s);

        for (int i = 0; i < M; ++i) {
            unsigned int km = __shfl(keep, i & 63, 64);
            const int kept_i = (km >> (i >> 6)) & 1u;
            float x1 = s_bx[i * 4 + 0], y1 = s_bx[i * 4 + 1];   // broadcast reads
            float x2 = s_bx[i * 4 + 2], y2 = s_bx[i * 4 + 3];
            float ai = (y2 - y1) * (x2 - x1);
            for (int s = 0; s < nslots; ++s) {
                int j = (s << 6) + lane;
                if (j > i && j < M) {
                    float bx1 = s_bx[j * 4 + 0], by1 = s_bx[j * 4 + 1];
                    float bx2 = s_bx[j * 4 + 2], by2 = s_bx[j * 4 + 3];
                    float aj = (by2 - by1) * (bx2 - bx1);
                    float ih = fminf(y2, by2) - fmaxf(y1, by1);
                    ih = fmaxf(ih, 0.0f);
                    float iw = fminf(x2, bx2) - fmaxf(x1, bx1);
                    iw = fmaxf(iw, 0.0f);
                    float inter = ih * iw;
                    float uni = ai + aj - inter;
                    float iou = (inter > 0.0f) ? inter / fmaxf(uni, 1e-08f) : 0.0f;
                    if (kept_i && iou > NMS_IOU_TH) keep &= ~(1u << s);
                }
            }
        }
        for (int s = 0; s < nslots; ++s) {
            int j = (s << 6) + lane;
            if (j < M) s_keep[j] = (unsigned char)((keep >> s) & 1u);
        }
    }
    __syncthreads();

    // --- emit top-100 kept in sorted order via wave-scan; pad with -1 ---
    const int chunk = (M + 255) / 256;           // contiguous slots per thread
    const int lo = threadIdx.x * chunk;
    const int hi = (lo + chunk < M) ? (lo + chunk) : M;
    int cnt = 0;
    for (int j = lo; j < hi; ++j) cnt += s_keep[j];
    s_part[threadIdx.x] = cnt;
    __syncthreads();
    if (threadIdx.x < 64) {
        const int base = threadIdx.x * 4;
        int v0 = s_part[base + 0], v1 = s_part[base + 1];
        int v2 = s_part[base + 2], v3 = s_part[base + 3];
        int sum = v0 + v1 + v2 + v3;
        int inc = sum;
        for (int off = 1; off < 64; off <<= 1) {
            int n = __shfl_up(inc, off, 64);
            if ((int)threadIdx.x >= off) inc += n;
        }
        int exc = inc - sum;
        s_part[base + 0] = exc;
        s_part[base + 1] = exc + v0;
        s_part[base + 2] = exc + v0 + v1;
        s_part[base + 3] = exc + v0 + v1 + v2;
        if (threadIdx.x == 63) s_total = inc;
    }
    __syncthreads();

    float* osc = ws_scores + ((size_t)b * NMS_NUM_CLASSES + c) * NMS_MAX_PER_CLASS;
    float* obx = ws_boxes + (((size_t)b * NMS_NUM_CLASSES + c) * NMS_MAX_PER_CLASS) * 4;
    int pos = s_part[threadIdx.x];
    for (int j = lo; j < hi; ++j) {
        if (s_keep[j]) {
            if (pos < NMS_MAX_PER_CLASS) {
                osc[pos] = s_sc[j];
                obx[pos * 4 + 0] = s_bx[j * 4 + 0];
                obx[pos * 4 + 1] = s_bx[j * 4 + 1];
                obx[pos * 4 + 2] = s_bx[j * 4 + 2];
                obx[pos * 4 + 3] = s_bx[j * 4 + 3];
            }
            pos++;
        }
    }
    // pad positions [total, 100) with -1
    if (threadIdx.x < NMS_MAX_PER_CLASS && threadIdx.x >= s_total)
        osc[threadIdx.x] = -1.0f;
}

// ---------------------------------------------------------------------------
// Kernel 2: one block per (image, class). Cross-class top-100 of the 1600
// slot scores (ties -> lower flat slot index, matching JAX top_k); scatter
// rows; nvalid via ballot. (unchanged from round 4/8 — verified absmax 0)
// ---------------------------------------------------------------------------
__global__ __launch_bounds__(128) void nms_topk_kernel(
    const float* __restrict__ ws_scores,   // [B, 1600]
    const float* __restrict__ ws_boxes,    // [B, 1600, 4]
    float* __restrict__ out,               // [B*600] rows + [B] nvalid
    int B)
{
    const int b = blockIdx.x / NMS_NUM_CLASSES;
    const int c = blockIdx.x % NMS_NUM_CLASSES;
    __shared__ float s_sc[NMS_NS];

    const float* isc = ws_scores + (size_t)b * NMS_NS;
    for (int t = threadIdx.x; t < NMS_NS; t += blockDim.x) s_sc[t] = isc[t];
    __syncthreads();

    int is_top = 0;
    const int t = threadIdx.x;
    if (t < NMS_MAX_PER_CLASS) {
        const int slot = c * NMS_MAX_PER_CLASS + t;
        float s = s_sc[slot];
        if (s > NMS_SCORE_TH) {
            int rk = 0;
            for (int j = 0; j < NMS_NS; ++j) {
                float sj = s_sc[j];
                rk += (sj > s) || (sj == s && j < slot);
            }
            if (rk < NMS_MAX_DET) {
                const float* bx = ws_boxes + ((size_t)b * NMS_NS + slot) * 4;
                float* row = out + (size_t)b * NMS_MAX_DET * 6 + rk * 6;
                row[0] = bx[0];
                row[1] = bx[1];
                row[2] = bx[2];
                row[3] = bx[3];
                row[4] = (float)c;
                row[5] = s;
                is_top = 1;
            }
        }
    }
    unsigned long long m = __ballot(is_top);
    if ((threadIdx.x & 63) == 0) {
        float cnt = (float)__popcll(m);
        if (cnt > 0.0f)
            atomicAdd(&out[(size_t)B * NMS_MAX_DET * 6 + b], cnt);
    }
}

extern "C" void kernel_launch(void* const* d_in, const int* in_sizes, int n_in,
                              void* d_out, int out_size, void* d_ws, size_t ws_size,
                              hipStream_t stream) {
    const float* pred = (const float*)d_in[0];
    const int B = in_sizes[0] / (NMS_N * 6);
    if (B <= 0) return;
    float* out = (float*)d_out;

    float* ws_scores = (float*)d_ws;
    float* ws_boxes = ws_scores + (size_t)B * NMS_NS;

    nms_per_class_kernel<<<dim3(B * NMS_NUM_CLASSES), dim3(256), 0, stream>>>(
        pred, ws_scores, ws_boxes, out, B);
    nms_topk_kernel<<<dim3(B * NMS_NUM_CLASSES), dim3(128), 0, stream>>>(
        ws_scores, ws_boxes, out, B);
}

// Round 12
// 155.241 us; speedup vs baseline: 2.4329x; 1.1261x over previous
//
#include <hip/hip_runtime.h>

#define NMS_NUM_CLASSES 16
#define NMS_N 2048
#define NMS_IOU_TH 0.5f
#define NMS_SCORE_TH 0.05f
#define NMS_MAX_DET 100
#define NMS_MAX_PER_CLASS 100
#define NMS_NS (NMS_NUM_CLASSES * NMS_MAX_PER_CLASS)   // 1600

// NOTE (session pitfall): casting __shared__ float arrays to float4* emits
// ds_read_b128 with an alignment promise the LDS allocator does not keep —
// 5/5 kernels with that cast died with container-level faults; all scalar-
// LDS kernels passed. Scalar LDS reads only in this file.

// ---------------------------------------------------------------------------
// Kernel 1: one block per (image, class). Compact -> rank sort -> wave-0
// serial greedy NMS with register keep-masks -> wave-scan emit.
// BYTE-IDENTICAL to round-11 (passed, 81.5 us, absmax 0).
// ---------------------------------------------------------------------------
__global__ __launch_bounds__(256) void nms_per_class_kernel(
    const float* __restrict__ pred,   // [B, N, 6] x1,y1,x2,y2,cls,score
    float* __restrict__ ws_scores,    // [B, 1600]
    float* __restrict__ ws_boxes,     // [B, 1600, 4]
    float* __restrict__ out,          // [B*600] rows + [B] nvalid
    int B)
{
    const int b = blockIdx.x / NMS_NUM_CLASSES;
    const int c = blockIdx.x % NMS_NUM_CLASSES;
    const float* p = pred + (size_t)b * NMS_N * 6;

    // zero-init output for this image (k2 is a later dispatch on the stream)
    if (c == 0) {
        float* ob = out + (size_t)b * NMS_MAX_DET * 6;
        for (int t = threadIdx.x; t < NMS_MAX_DET * 6; t += blockDim.x) ob[t] = 0.0f;
        if (threadIdx.x == 0) out[(size_t)B * NMS_MAX_DET * 6 + b] = 0.0f;
    }

    // unsorted candidate arrays
    __shared__ float s_scu[NMS_N];
    __shared__ int   s_ixu[NMS_N];
    __shared__ float s_bxu[NMS_N * 4];
    // sorted candidate arrays
    __shared__ float s_sc[NMS_N];
    __shared__ float s_bx[NMS_N * 4];
    __shared__ unsigned char s_keep[NMS_N];
    __shared__ int s_m;
    __shared__ int s_part[256];
    __shared__ int s_total;

    if (threadIdx.x == 0) s_m = 0;
    __syncthreads();

    // --- compact candidates of class c with score > TH ---
    const float2* p2 = (const float2*)p;   // row i = p2[3i], p2[3i+1], p2[3i+2]
    for (int i = threadIdx.x; i < NMS_N; i += blockDim.x) {
        float2 v0 = p2[i * 3 + 0];   // x1, y1
        float2 v1 = p2[i * 3 + 1];   // x2, y2
        float2 v2 = p2[i * 3 + 2];   // cls, score
        if ((int)v2.x == c && v2.y > NMS_SCORE_TH) {
            int pos = atomicAdd(&s_m, 1);
            s_scu[pos] = v2.y;
            s_ixu[pos] = i;
            s_bxu[pos * 4 + 0] = v0.x;
            s_bxu[pos * 4 + 1] = v0.y;
            s_bxu[pos * 4 + 2] = v1.x;
            s_bxu[pos * 4 + 3] = v1.y;
        }
    }
    __syncthreads();
    const int M = s_m;

    // --- rank sort: desc score, ties -> lower original index first ---
    for (int q = threadIdx.x; q < M; q += blockDim.x) {
        float sq = s_scu[q];
        int   iq = s_ixu[q];
        int rk = 0;
        for (int j = 0; j < M; ++j) {
            float sj = s_scu[j];
            rk += (sj > sq) || (sj == sq && s_ixu[j] < iq);
        }
        s_sc[rk] = sq;
        s_bx[rk * 4 + 0] = s_bxu[q * 4 + 0];
        s_bx[rk * 4 + 1] = s_bxu[q * 4 + 1];
        s_bx[rk * 4 + 2] = s_bxu[q * 4 + 2];
        s_bx[rk * 4 + 3] = s_bxu[q * 4 + 3];
    }
    __syncthreads();

    // --- wave-0 serial greedy NMS, register keep-masks ---
    if (threadIdx.x < 64) {
        const int lane = threadIdx.x;
        const int nslots = (M + 63) >> 6;
        unsigned int keep = 0;
        for (int s = 0; s < nslots; ++s)
            if ((s << 6) + lane < M) keep |= (1u << s);

        for (int i = 0; i < M; ++i) {
            unsigned int km = __shfl(keep, i & 63, 64);
            const int kept_i = (km >> (i >> 6)) & 1u;
            float x1 = s_bx[i * 4 + 0], y1 = s_bx[i * 4 + 1];   // broadcast reads
            float x2 = s_bx[i * 4 + 2], y2 = s_bx[i * 4 + 3];
            float ai = (y2 - y1) * (x2 - x1);
            for (int s = 0; s < nslots; ++s) {
                int j = (s << 6) + lane;
                if (j > i && j < M) {
                    float bx1 = s_bx[j * 4 + 0], by1 = s_bx[j * 4 + 1];
                    float bx2 = s_bx[j * 4 + 2], by2 = s_bx[j * 4 + 3];
                    float aj = (by2 - by1) * (bx2 - bx1);
                    float ih = fminf(y2, by2) - fmaxf(y1, by1);
                    ih = fmaxf(ih, 0.0f);
                    float iw = fminf(x2, bx2) - fmaxf(x1, bx1);
                    iw = fmaxf(iw, 0.0f);
                    float inter = ih * iw;
                    float uni = ai + aj - inter;
                    float iou = (inter > 0.0f) ? inter / fmaxf(uni, 1e-08f) : 0.0f;
                    if (kept_i && iou > NMS_IOU_TH) keep &= ~(1u << s);
                }
            }
        }
        for (int s = 0; s < nslots; ++s) {
            int j = (s << 6) + lane;
            if (j < M) s_keep[j] = (unsigned char)((keep >> s) & 1u);
        }
    }
    __syncthreads();

    // --- emit top-100 kept in sorted order via wave-scan; pad with -1 ---
    const int chunk = (M + 255) / 256;           // contiguous slots per thread
    const int lo = threadIdx.x * chunk;
    const int hi = (lo + chunk < M) ? (lo + chunk) : M;
    int cnt = 0;
    for (int j = lo; j < hi; ++j) cnt += s_keep[j];
    s_part[threadIdx.x] = cnt;
    __syncthreads();
    if (threadIdx.x < 64) {
        const int base = threadIdx.x * 4;
        int v0 = s_part[base + 0], v1 = s_part[base + 1];
        int v2 = s_part[base + 2], v3 = s_part[base + 3];
        int sum = v0 + v1 + v2 + v3;
        int inc = sum;
        for (int off = 1; off < 64; off <<= 1) {
            int n = __shfl_up(inc, off, 64);
            if ((int)threadIdx.x >= off) inc += n;
        }
        int exc = inc - sum;
        s_part[base + 0] = exc;
        s_part[base + 1] = exc + v0;
        s_part[base + 2] = exc + v0 + v1;
        s_part[base + 3] = exc + v0 + v1 + v2;
        if (threadIdx.x == 63) s_total = inc;
    }
    __syncthreads();

    float* osc = ws_scores + ((size_t)b * NMS_NUM_CLASSES + c) * NMS_MAX_PER_CLASS;
    float* obx = ws_boxes + (((size_t)b * NMS_NUM_CLASSES + c) * NMS_MAX_PER_CLASS) * 4;
    int pos = s_part[threadIdx.x];
    for (int j = lo; j < hi; ++j) {
        if (s_keep[j]) {
            if (pos < NMS_MAX_PER_CLASS) {
                osc[pos] = s_sc[j];
                obx[pos * 4 + 0] = s_bx[j * 4 + 0];
                obx[pos * 4 + 1] = s_bx[j * 4 + 1];
                obx[pos * 4 + 2] = s_bx[j * 4 + 2];
                obx[pos * 4 + 3] = s_bx[j * 4 + 3];
            }
            pos++;
        }
    }
    // pad positions [total, 100) with -1
    if (threadIdx.x < NMS_MAX_PER_CLASS && threadIdx.x >= s_total)
        osc[threadIdx.x] = -1.0f;
}

// ---------------------------------------------------------------------------
// Kernel 2: one block per (image, class), 256 threads. Rank of each of this
// class's 100 slots among the image's 1600 is a SUM of independent
// indicators -> decompose into 1600 (slot, j-chunk-of-100) tasks over 256
// threads; each task does 100 independent LDS reads + one LDS atomicAdd.
// Removes the per-thread 1600-long dependent-load chain of the old k2.
// Tie-break (lower flat slot index first) and scatter identical to the
// r4/r11-verified version.
// ---------------------------------------------------------------------------
__global__ __launch_bounds__(256) void nms_topk_kernel(
    const float* __restrict__ ws_scores,   // [B, 1600]
    const float* __restrict__ ws_boxes,    // [B, 1600, 4]
    float* __restrict__ out,               // [B*600] rows + [B] nvalid
    int B)
{
    const int b = blockIdx.x / NMS_NUM_CLASSES;
    const int c = blockIdx.x % NMS_NUM_CLASSES;
    const int cbase = c * NMS_MAX_PER_CLASS;
    __shared__ float s_sc[NMS_NS];
    __shared__ int s_rank[NMS_MAX_PER_CLASS];

    const float* isc = ws_scores + (size_t)b * NMS_NS;
    for (int t = threadIdx.x; t < NMS_NS; t += blockDim.x) s_sc[t] = isc[t];
    if (threadIdx.x < NMS_MAX_PER_CLASS) s_rank[threadIdx.x] = 0;
    __syncthreads();

    // 1600 tasks: task = chunk*100 + slot (consecutive tids -> distinct slots,
    // spreading the atomicAdd addresses within a wave)
    for (int task = threadIdx.x; task < NMS_MAX_PER_CLASS * 16; task += blockDim.x) {
        const int slot = task % NMS_MAX_PER_CLASS;
        const int chunk = task / NMS_MAX_PER_CLASS;
        const int flat = cbase + slot;
        const float s = s_sc[flat];
        const int j0 = chunk * 100;
        int rk = 0;
        for (int j = j0; j < j0 + 100; ++j) {
            float sj = s_sc[j];
            rk += (sj > s) || (sj == s && j < flat);
        }
        if (rk) atomicAdd(&s_rank[slot], rk);
    }
    __syncthreads();

    int is_top = 0;
    const int t = threadIdx.x;
    if (t < NMS_MAX_PER_CLASS) {
        const int slot = cbase + t;
        float s = s_sc[slot];
        if (s > NMS_SCORE_TH) {
            int rk = s_rank[t];
            if (rk < NMS_MAX_DET) {
                const float* bx = ws_boxes + ((size_t)b * NMS_NS + slot) * 4;
                float* row = out + (size_t)b * NMS_MAX_DET * 6 + rk * 6;
                row[0] = bx[0];
                row[1] = bx[1];
                row[2] = bx[2];
                row[3] = bx[3];
                row[4] = (float)c;
                row[5] = s;
                is_top = 1;
            }
        }
    }
    unsigned long long m = __ballot(is_top);
    if ((threadIdx.x & 63) == 0) {
        float cnt = (float)__popcll(m);
        if (cnt > 0.0f)
            atomicAdd(&out[(size_t)B * NMS_MAX_DET * 6 + b], cnt);
    }
}

extern "C" void kernel_launch(void* const* d_in, const int* in_sizes, int n_in,
                              void* d_out, int out_size, void* d_ws, size_t ws_size,
                              hipStream_t stream) {
    const float* pred = (const float*)d_in[0];
    const int B = in_sizes[0] / (NMS_N * 6);
    if (B <= 0) return;
    float* out = (float*)d_out;

    float* ws_scores = (float*)d_ws;
    float* ws_boxes = ws_scores + (size_t)B * NMS_NS;

    nms_per_class_kernel<<<dim3(B * NMS_NUM_CLASSES), dim3(256), 0, stream>>>(
        pred, ws_scores, ws_boxes, out, B);
    nms_topk_kernel<<<dim3(B * NMS_NUM_CLASSES), dim3(256), 0, stream>>>(
        ws_scores, ws_boxes, out, B);
}